// Round 1
// 486.002 us; speedup vs baseline: 1.0788x; 1.0788x over previous
//
#include <hip/hip_runtime.h>
#include <math.h>

#define B 8192
#define D 512
#define NH 4
#define M 128
#define W 64
#define HW 256   // NH * W
#define EPS 1e-6f

// ---------------------------------------------------------------------------
// K1: key = tanh(hidden @ W_key + b_key)   -> key_ws  [B][256]
//     u2  = sum(key^2) + EPS per head      -> u2_ws   [B][4]   (hoisted here)
//     beta = softplus(hidden @ W_beta+b_b) -> beta_ws [B][4]
//
// 512 blocks x 512 threads (8 waves) = 2 blocks/CU -> 4 waves/SIMD (vs 2
// before). Block computes a 16-row x 256-col key tile. Thread (tx=t&63,
// ty=t>>6) owns a 2-row x 4-col register tile:
//   per d: 1 coalesced float4 Wk load + 2 LDS-broadcast hidden reads + 8 FMA.
// Hidden tile (16x512, 32 KB) is staged into LDS with coalesced float4 loads;
// inner-loop reads are wave-uniform -> bank-conflict-free broadcast.
// u2 per (row,head): lanes of one 16-lane group hold that head's 64 columns
// -> 4-step shfl_xor reduce, lane (tx&15)==0 stores.
// Beta tail reads hidden from global (L2-warm); LDS would be a 32-way
// bank conflict for this access pattern.
// ---------------------------------------------------------------------------
__global__ __launch_bounds__(512) void key_beta_gemm(const float* __restrict__ hid,
                                                     const float* __restrict__ Wk,
                                                     const float* __restrict__ bk,
                                                     const float* __restrict__ Wb,
                                                     const float* __restrict__ bb,
                                                     float* __restrict__ key,
                                                     float* __restrict__ beta,
                                                     float* __restrict__ u2w) {
    const int t  = threadIdx.x;
    const int tx = t & 63;        // column group: cols 4*tx .. 4*tx+3
    const int ty = t >> 6;        // 0..7 -> rows 2*ty, 2*ty+1
    const int i0 = blockIdx.x * 16;

    __shared__ float hl[16 * D];  // 32 KB hidden tile

    {   // cooperative stage: 2048 float4 / 512 threads = 4 each, coalesced
        const float4* src = (const float4*)(hid + (size_t)i0 * D);
        float4* dst = (float4*)hl;
#pragma unroll
        for (int c = 0; c < 4; ++c)
            dst[t + c * 512] = src[t + c * 512];
    }
    __syncthreads();

    const float* h0 = hl + (2 * ty) * D;
    const float* h1 = h0 + D;
    const float4* wk4 = (const float4*)Wk + tx;

    float4 a0 = make_float4(0.f, 0.f, 0.f, 0.f);
    float4 a1 = make_float4(0.f, 0.f, 0.f, 0.f);
#pragma unroll 4
    for (int d = 0; d < D; ++d) {
        const float4 w = wk4[(size_t)d * (HW / 4)];
        const float x0 = h0[d];
        const float x1 = h1[d];
        a0.x = fmaf(x0, w.x, a0.x);
        a0.y = fmaf(x0, w.y, a0.y);
        a0.z = fmaf(x0, w.z, a0.z);
        a0.w = fmaf(x0, w.w, a0.w);
        a1.x = fmaf(x1, w.x, a1.x);
        a1.y = fmaf(x1, w.y, a1.y);
        a1.z = fmaf(x1, w.z, a1.z);
        a1.w = fmaf(x1, w.w, a1.w);
    }

    const float4 bv = ((const float4*)bk)[tx];
    float4 k0, k1;
    k0.x = tanhf(a0.x + bv.x);  k0.y = tanhf(a0.y + bv.y);
    k0.z = tanhf(a0.z + bv.z);  k0.w = tanhf(a0.w + bv.w);
    k1.x = tanhf(a1.x + bv.x);  k1.y = tanhf(a1.y + bv.y);
    k1.z = tanhf(a1.z + bv.z);  k1.w = tanhf(a1.w + bv.w);

    *(float4*)(key + (size_t)(i0 + 2 * ty) * HW + 4 * tx)     = k0;
    *(float4*)(key + (size_t)(i0 + 2 * ty + 1) * HW + 4 * tx) = k1;

    // ---- u2 per (row, head): reduce k^2 over the 16-lane head group -------
    float s0 = k0.x * k0.x + k0.y * k0.y + k0.z * k0.z + k0.w * k0.w;
    float s1 = k1.x * k1.x + k1.y * k1.y + k1.z * k1.z + k1.w * k1.w;
#pragma unroll
    for (int off = 1; off < 16; off <<= 1) {
        s0 += __shfl_xor(s0, off, 64);
        s1 += __shfl_xor(s1, off, 64);
    }
    if ((tx & 15) == 0) {
        const int h = tx >> 4;
        u2w[(size_t)(i0 + 2 * ty) * NH + h]     = s0 + EPS;
        u2w[(size_t)(i0 + 2 * ty + 1) * NH + h] = s1 + EPS;
    }

    // ---- beta tail: t -> (row ii, head hh, eighth q of D) -----------------
    const int ii = t >> 5;        // 0..15
    const int hh = (t >> 3) & 3;  // 0..3
    const int q  = t & 7;         // 0..7 -> d in [q*64, q*64+64)
    const float* hrow = hid + (size_t)(i0 + ii) * D + q * 64;
    const float* wcol = Wb + (size_t)(q * 64) * NH + hh;
    float acc2 = 0.f;
#pragma unroll 4
    for (int d = 0; d < 64; ++d)
        acc2 = fmaf(hrow[d], wcol[(size_t)d * NH], acc2);
    acc2 += __shfl_xor(acc2, 1, 64);
    acc2 += __shfl_xor(acc2, 2, 64);
    acc2 += __shfl_xor(acc2, 4, 64);
    if (q == 0) {
        const float x = acc2 + bb[hh];
        // stable softplus: max(x,0) + log1p(exp(-|x|))
        beta[(size_t)(i0 + ii) * NH + hh] = fmaxf(x, 0.f) + log1pf(expf(-fabsf(x)));
    }
}

// ---------------------------------------------------------------------------
// K2: cosine similarity + scaled softmax. 2 batches per 256-thread block
// (4096 blocks); each 128-thread half owns one batch, thread t = memory row.
// u2/beta arrive precomputed as one float4 each; the serial u2 section and
// one barrier are gone. Row loads stay 16 x float4 fully unrolled (all lines
// per lane in flight together -> full line utilization via MSHR merge).
// ---------------------------------------------------------------------------
__global__ __launch_bounds__(256) void attn_kernel(const float* __restrict__ mem,
                                                   const float* __restrict__ key,
                                                   const float* __restrict__ beta,
                                                   const float* __restrict__ u2w,
                                                   float* __restrict__ out) {
    const int tid  = threadIdx.x;
    const int half = tid >> 7;     // which batch of the pair
    const int t    = tid & 127;    // memory row m
    const int b    = blockIdx.x * 2 + half;

    __shared__ float ksh[2][HW];
    __shared__ float red[2][2][NH];

    ksh[half][t]       = key[(size_t)b * HW + t];
    ksh[half][t + 128] = key[(size_t)b * HW + t + 128];
    const float4 bet = *(const float4*)&beta[(size_t)b * NH];
    const float4 uu  = *(const float4*)&u2w[(size_t)b * NH];
    __syncthreads();

    const float4* row = (const float4*)(mem + (size_t)b * (M * W) + (size_t)t * W);
    float v2 = 0.f;
    float nh[NH] = {0.f, 0.f, 0.f, 0.f};
#pragma unroll
    for (int c = 0; c < 16; ++c) {
        const float4 x = row[c];
        v2 = fmaf(x.x, x.x, fmaf(x.y, x.y, fmaf(x.z, x.z, fmaf(x.w, x.w, v2))));
#pragma unroll
        for (int h = 0; h < NH; ++h) {
            const float4 kk = *(const float4*)&ksh[half][h * W + c * 4];
            nh[h] = fmaf(x.x, kk.x, fmaf(x.y, kk.y, fmaf(x.z, kk.z, fmaf(x.w, kk.w, nh[h]))));
        }
    }
    v2 += EPS;

    const float ub[NH]  = {uu.x, uu.y, uu.z, uu.w};
    const float bt4[NH] = {bet.x, bet.y, bet.z, bet.w};
    float logit[NH];
#pragma unroll
    for (int h = 0; h < NH; ++h) {
        const float den = sqrtf(ub[h] * v2);
        logit[h] = (nh[h] / (den + EPS)) * bt4[h];
    }

    // softmax over m per head; each half has 2 waves -> shuffle + LDS combine
    const int lane = tid & 63;
    const int wid  = (tid >> 6) & 1;

    float mx[NH];
#pragma unroll
    for (int h = 0; h < NH; ++h) {
        float m_ = logit[h];
#pragma unroll
        for (int off = 1; off < 64; off <<= 1)
            m_ = fmaxf(m_, __shfl_xor(m_, off, 64));
        mx[h] = m_;
    }
    if (lane == 0) {
#pragma unroll
        for (int h = 0; h < NH; ++h) red[half][wid][h] = mx[h];
    }
    __syncthreads();

    float e[NH];
#pragma unroll
    for (int h = 0; h < NH; ++h) {
        const float gm = fmaxf(red[half][0][h], red[half][1][h]);
        e[h] = expf(logit[h] - gm);
    }
    __syncthreads();  // red reads done before overwrite

    float sm[NH];
#pragma unroll
    for (int h = 0; h < NH; ++h) {
        float s_ = e[h];
#pragma unroll
        for (int off = 1; off < 64; off <<= 1)
            s_ += __shfl_xor(s_, off, 64);
        sm[h] = s_;
    }
    if (lane == 0) {
#pragma unroll
        for (int h = 0; h < NH; ++h) red[half][wid][h] = sm[h];
    }
    __syncthreads();

#pragma unroll
    for (int h = 0; h < NH; ++h) {
        const float tot = red[half][0][h] + red[half][1][h];
        out[(size_t)b * (NH * M) + (size_t)h * M + t] = e[h] / tot;
    }
}

// ---------------------------------------------------------------------------
extern "C" void kernel_launch(void* const* d_in, const int* in_sizes, int n_in,
                              void* d_out, int out_size, void* d_ws, size_t ws_size,
                              hipStream_t stream) {
    const float* hid = (const float*)d_in[0];  // [B, D]
    const float* mem = (const float*)d_in[1];  // [B, M, W]
    const float* Wk  = (const float*)d_in[2];  // [D, HW]
    const float* bk  = (const float*)d_in[3];  // [HW]
    const float* Wb  = (const float*)d_in[4];  // [D, NH]
    const float* bb  = (const float*)d_in[5];  // [NH]
    float* out = (float*)d_out;                // [B, NH, M]

    float* key_ws  = (float*)d_ws;                     // B*HW floats (8 MB)
    float* beta_ws = key_ws + (size_t)B * HW;          // B*NH floats
    float* u2_ws   = beta_ws + (size_t)B * NH;         // B*NH floats

    key_beta_gemm<<<B / 16, 512, 0, stream>>>(hid, Wk, bk, Wb, bb,
                                              key_ws, beta_ws, u2_ws);
    attn_kernel<<<B / 2, 256, 0, stream>>>(mem, key_ws, beta_ws, u2_ws, out);
}

// Round 2
// 456.784 us; speedup vs baseline: 1.1478x; 1.0640x over previous
//
#include <hip/hip_runtime.h>
#include <math.h>

#define B 8192
#define D 512
#define NH 4
#define M 128
#define W 64
#define HW 256   // NH * W
#define EPS 1e-6f

// ---------------------------------------------------------------------------
// K1: key = tanh(hidden @ W_key + b_key)   -> key_ws  [B][256]
//     u2  = sum(key^2) + EPS per head      -> u2_ws   [B][4]
//     beta = softplus(hidden @ W_beta+b_b) -> beta_ws [B][4]
//
// 512 blocks x 512 threads; block = 16 rows x 256 cols. Thread tile is
// 8 rows x 1 col (tx = t&255 -> column, ty = t>>8 -> row octet):
//   per 4 d's: 4 scalar Wk loads (coalesced 256 B/wave-instr) +
//              8 uniform-broadcast ds_read_b128 (hidden) + 32 FMA.
// Rationale: vL1D demand scales as 512/rows_per_thread B/cyc/CU; the old
// 2-row tile demanded ~256 B/cyc/CU (L1-bound). 8 rows -> ~64 B/cyc/CU,
// VALU-bound at the fp32 floor. Occupancy unchanged (4 waves/SIMD).
// u2: one wave spans exactly one head's 64 cols -> full-wave butterfly.
// ---------------------------------------------------------------------------
__global__ __launch_bounds__(512) void key_beta_gemm(const float* __restrict__ hid,
                                                     const float* __restrict__ Wk,
                                                     const float* __restrict__ bk,
                                                     const float* __restrict__ Wb,
                                                     const float* __restrict__ bb,
                                                     float* __restrict__ key,
                                                     float* __restrict__ beta,
                                                     float* __restrict__ u2w) {
    const int t  = threadIdx.x;
    const int tx = t & 255;       // output column 0..255
    const int ty = t >> 8;        // 0..1 -> rows 8*ty .. 8*ty+7
    const int i0 = blockIdx.x * 16;

    __shared__ float hl[16 * D];  // 32 KB hidden tile

    {   // cooperative stage: 2048 float4 / 512 threads = 4 each, coalesced
        const float4* src = (const float4*)(hid + (size_t)i0 * D);
        float4* dst = (float4*)hl;
#pragma unroll
        for (int c = 0; c < 4; ++c)
            dst[t + c * 512] = src[t + c * 512];
    }
    __syncthreads();

    const float* hrows = hl + (8 * ty) * D;
    const float* wcol  = Wk + tx;

    float acc[8];
#pragma unroll
    for (int r = 0; r < 8; ++r) acc[r] = 0.f;

#pragma unroll 2
    for (int d = 0; d < D; d += 4) {
        const float w0 = wcol[(size_t)(d + 0) * HW];
        const float w1 = wcol[(size_t)(d + 1) * HW];
        const float w2 = wcol[(size_t)(d + 2) * HW];
        const float w3 = wcol[(size_t)(d + 3) * HW];
#pragma unroll
        for (int r = 0; r < 8; ++r) {
            const float4 x = *(const float4*)&hrows[r * D + d];
            acc[r] = fmaf(x.w, w3, fmaf(x.z, w2, fmaf(x.y, w1, fmaf(x.x, w0, acc[r]))));
        }
    }

    const float bj = bk[tx];
    float k[8];
#pragma unroll
    for (int r = 0; r < 8; ++r) {
        k[r] = tanhf(acc[r] + bj);
        key[(size_t)(i0 + 8 * ty + r) * HW + tx] = k[r];
    }

    // ---- u2 per (row, head): wave = one head's 64 columns -----------------
    float s[8];
#pragma unroll
    for (int r = 0; r < 8; ++r) s[r] = k[r] * k[r];
#pragma unroll
    for (int off = 1; off < 64; off <<= 1) {
#pragma unroll
        for (int r = 0; r < 8; ++r) s[r] += __shfl_xor(s[r], off, 64);
    }
    if ((t & 63) == 0) {
        const int h = (t >> 6) & 3;   // wave id within ty-half = head
#pragma unroll
        for (int r = 0; r < 8; ++r)
            u2w[(size_t)(i0 + 8 * ty + r) * NH + h] = s[r] + EPS;
    }

    // ---- beta tail: t -> (row ii, head hh, eighth q of D) -----------------
    const int ii = t >> 5;        // 0..15
    const int hh = (t >> 3) & 3;  // 0..3
    const int q  = t & 7;         // 0..7 -> d in [q*64, q*64+64)
    const float* hrow = hid + (size_t)(i0 + ii) * D + q * 64;
    const float* wcb  = Wb + (size_t)(q * 64) * NH + hh;
    float acc2 = 0.f;
#pragma unroll 4
    for (int d = 0; d < 64; ++d)
        acc2 = fmaf(hrow[d], wcb[(size_t)d * NH], acc2);
    acc2 += __shfl_xor(acc2, 1, 64);
    acc2 += __shfl_xor(acc2, 2, 64);
    acc2 += __shfl_xor(acc2, 4, 64);
    if (q == 0) {
        const float x = acc2 + bb[hh];
        // stable softplus: max(x,0) + log1p(exp(-|x|))
        beta[(size_t)(i0 + ii) * NH + hh] = fmaxf(x, 0.f) + log1pf(expf(-fabsf(x)));
    }
}

// ---------------------------------------------------------------------------
// K2: cosine similarity + scaled softmax. 2 batches per 256-thread block
// (4096 blocks); each 128-thread half owns one batch, thread t = memory row.
// u2/beta precomputed (single float4 each). Row loads: 16 x float4 fully
// unrolled -> all lines per lane in flight together (MSHR merge), dense
// 16 KB per wave-group. Memory-bound at the 294 MB compulsory stream.
// ---------------------------------------------------------------------------
__global__ __launch_bounds__(256) void attn_kernel(const float* __restrict__ mem,
                                                   const float* __restrict__ key,
                                                   const float* __restrict__ beta,
                                                   const float* __restrict__ u2w,
                                                   float* __restrict__ out) {
    const int tid  = threadIdx.x;
    const int half = tid >> 7;     // which batch of the pair
    const int t    = tid & 127;    // memory row m
    const int b    = blockIdx.x * 2 + half;

    __shared__ float ksh[2][HW];
    __shared__ float red[2][2][NH];

    ksh[half][t]       = key[(size_t)b * HW + t];
    ksh[half][t + 128] = key[(size_t)b * HW + t + 128];
    const float4 bet = *(const float4*)&beta[(size_t)b * NH];
    const float4 uu  = *(const float4*)&u2w[(size_t)b * NH];
    __syncthreads();

    const float4* row = (const float4*)(mem + (size_t)b * (M * W) + (size_t)t * W);
    float v2 = 0.f;
    float nh[NH] = {0.f, 0.f, 0.f, 0.f};
#pragma unroll
    for (int c = 0; c < 16; ++c) {
        const float4 x = row[c];
        v2 = fmaf(x.x, x.x, fmaf(x.y, x.y, fmaf(x.z, x.z, fmaf(x.w, x.w, v2))));
#pragma unroll
        for (int h = 0; h < NH; ++h) {
            const float4 kk = *(const float4*)&ksh[half][h * W + c * 4];
            nh[h] = fmaf(x.x, kk.x, fmaf(x.y, kk.y, fmaf(x.z, kk.z, fmaf(x.w, kk.w, nh[h]))));
        }
    }
    v2 += EPS;

    const float ub[NH]  = {uu.x, uu.y, uu.z, uu.w};
    const float bt4[NH] = {bet.x, bet.y, bet.z, bet.w};
    float logit[NH];
#pragma unroll
    for (int h = 0; h < NH; ++h) {
        const float den = sqrtf(ub[h] * v2);
        logit[h] = (nh[h] / (den + EPS)) * bt4[h];
    }

    // softmax over m per head; each half has 2 waves -> shuffle + LDS combine
    const int lane = tid & 63;
    const int wid  = (tid >> 6) & 1;

    float mx[NH];
#pragma unroll
    for (int h = 0; h < NH; ++h) {
        float m_ = logit[h];
#pragma unroll
        for (int off = 1; off < 64; off <<= 1)
            m_ = fmaxf(m_, __shfl_xor(m_, off, 64));
        mx[h] = m_;
    }
    if (lane == 0) {
#pragma unroll
        for (int h = 0; h < NH; ++h) red[half][wid][h] = mx[h];
    }
    __syncthreads();

    float e[NH];
#pragma unroll
    for (int h = 0; h < NH; ++h) {
        const float gm = fmaxf(red[half][0][h], red[half][1][h]);
        e[h] = expf(logit[h] - gm);
    }
    __syncthreads();  // red reads done before overwrite

    float sm[NH];
#pragma unroll
    for (int h = 0; h < NH; ++h) {
        float s_ = e[h];
#pragma unroll
        for (int off = 1; off < 64; off <<= 1)
            s_ += __shfl_xor(s_, off, 64);
        sm[h] = s_;
    }
    if (lane == 0) {
#pragma unroll
        for (int h = 0; h < NH; ++h) red[half][wid][h] = sm[h];
    }
    __syncthreads();

#pragma unroll
    for (int h = 0; h < NH; ++h) {
        const float tot = red[half][0][h] + red[half][1][h];
        out[(size_t)b * (NH * M) + (size_t)h * M + t] = e[h] / tot;
    }
}

// ---------------------------------------------------------------------------
extern "C" void kernel_launch(void* const* d_in, const int* in_sizes, int n_in,
                              void* d_out, int out_size, void* d_ws, size_t ws_size,
                              hipStream_t stream) {
    const float* hid = (const float*)d_in[0];  // [B, D]
    const float* mem = (const float*)d_in[1];  // [B, M, W]
    const float* Wk  = (const float*)d_in[2];  // [D, HW]
    const float* bk  = (const float*)d_in[3];  // [HW]
    const float* Wb  = (const float*)d_in[4];  // [D, NH]
    const float* bb  = (const float*)d_in[5];  // [NH]
    float* out = (float*)d_out;                // [B, NH, M]

    float* key_ws  = (float*)d_ws;                     // B*HW floats (8 MB)
    float* beta_ws = key_ws + (size_t)B * HW;          // B*NH floats
    float* u2_ws   = beta_ws + (size_t)B * NH;         // B*NH floats

    key_beta_gemm<<<B / 16, 512, 0, stream>>>(hid, Wk, bk, Wb, bb,
                                              key_ws, beta_ws, u2_ws);
    attn_kernel<<<B / 2, 256, 0, stream>>>(mem, key_ws, beta_ws, u2_ws, out);
}

// Round 3
// 445.812 us; speedup vs baseline: 1.1761x; 1.0246x over previous
//
#include <hip/hip_runtime.h>
#include <math.h>

#define B 8192
#define D 512
#define NH 4
#define M 128
#define W 64
#define HW 256   // NH * W
#define TILE 16  // batch rows per block
#define EPS 1e-6f

// ---------------------------------------------------------------------------
// Fully fused kernel: one block = 16 batches, 512 threads, 3 phases.
//
// Phase A: stage hidden tile (16 x 512, 32 KB) into LDS, coalesced float4.
// Phase B: key = tanh(hidden @ W_key + b);   8-row x 1-col per thread
//          (tx = t&255 column, ty = t>>8 row-octet). Per 4 d's: 4 scalar Wk
//          loads (256 B/wave-instr, L1/L2-resident) + 8 broadcast LDS reads
//          + 32 FMA -> VALU-bound at the fp32 floor (no fp32 MFMA on CDNA4).
//          key -> kl[row][col] in LDS (lanes tx consecutive -> 2-way, free).
//          u2 per (row, head): wave = one head's 64 cols -> full butterfly.
//          beta tail: hidden re-read from global (L1/L2-warm; LDS here would
//          be a 16-way bank conflict), 8-lane partial dots + shfl reduce.
// Phase C: attention, ONE WAVE PER BATCH (8 waves x 2 passes = 16 batches).
//          Lane owns memory rows {lane, lane+64}: 2x16 float4 fully unrolled
//          (all lines in flight -> MSHR merge), key read as uniform LDS
//          broadcast. Softmax is a pure in-wave butterfly over the 2
//          rows/lane -- zero barriers, zero LDS traffic in the whole phase.
//
// Fusion kills: 1 launch boundary, the 16.8 MB key/beta/u2 HBM round-trip,
// and K2's 4 syncthreads + LDS combines per batch. Workspace now unused.
// LDS 48.3 KB -> 3 blocks/CU (grid = 512 = 2/CU resident).
// ---------------------------------------------------------------------------
__global__ __launch_bounds__(512) void fused_dynhead(const float* __restrict__ hid,
                                                     const float* __restrict__ mem,
                                                     const float* __restrict__ Wk,
                                                     const float* __restrict__ bk,
                                                     const float* __restrict__ Wb,
                                                     const float* __restrict__ bb,
                                                     float* __restrict__ out) {
    const int t  = threadIdx.x;
    const int i0 = blockIdx.x * TILE;

    __shared__ float hl[TILE * D];      // 32 KB hidden tile
    __shared__ float kl[TILE][HW];      // 16 KB key tile
    __shared__ float u2s[TILE][NH];
    __shared__ float bts[TILE][NH];

    // ---- Phase A: stage hidden --------------------------------------------
    {
        const float4* src = (const float4*)(hid + (size_t)i0 * D);
        float4* dst = (float4*)hl;
#pragma unroll
        for (int c = 0; c < 4; ++c)
            dst[t + c * 512] = src[t + c * 512];
    }
    __syncthreads();

    // ---- Phase B: key GEMM + tanh + u2 + beta -----------------------------
    {
        const int tx = t & 255;       // output column 0..255
        const int ty = t >> 8;        // 0..1 -> rows 8*ty .. 8*ty+7
        const float* hrows = hl + (8 * ty) * D;
        const float* wcol  = Wk + tx;

        float acc[8];
#pragma unroll
        for (int r = 0; r < 8; ++r) acc[r] = 0.f;

#pragma unroll 2
        for (int d = 0; d < D; d += 4) {
            const float w0 = wcol[(size_t)(d + 0) * HW];
            const float w1 = wcol[(size_t)(d + 1) * HW];
            const float w2 = wcol[(size_t)(d + 2) * HW];
            const float w3 = wcol[(size_t)(d + 3) * HW];
#pragma unroll
            for (int r = 0; r < 8; ++r) {
                const float4 x = *(const float4*)&hrows[r * D + d];
                acc[r] = fmaf(x.w, w3, fmaf(x.z, w2, fmaf(x.y, w1, fmaf(x.x, w0, acc[r]))));
            }
        }

        const float bj = bk[tx];
        float k[8];
#pragma unroll
        for (int r = 0; r < 8; ++r) {
            k[r] = tanhf(acc[r] + bj);
            kl[8 * ty + r][tx] = k[r];
        }

        // u2 per (row, head): wave spans exactly one head's 64 columns
        float s[8];
#pragma unroll
        for (int r = 0; r < 8; ++r) s[r] = k[r] * k[r];
#pragma unroll
        for (int off = 1; off < 64; off <<= 1) {
#pragma unroll
            for (int r = 0; r < 8; ++r) s[r] += __shfl_xor(s[r], off, 64);
        }
        if ((t & 63) == 0) {
            const int h = (t >> 6) & 3;
#pragma unroll
            for (int r = 0; r < 8; ++r)
                u2s[8 * ty + r][h] = s[r] + EPS;
        }

        // beta tail: t -> (row ii, head hh, eighth q of D)
        const int ii = t >> 5;        // 0..15
        const int hh = (t >> 3) & 3;  // 0..3
        const int q  = t & 7;         // 0..7 -> d in [q*64, q*64+64)
        const float* hrow = hid + (size_t)(i0 + ii) * D + q * 64;
        const float* wcb  = Wb + (size_t)(q * 64) * NH + hh;
        float acc2 = 0.f;
#pragma unroll 4
        for (int d = 0; d < 64; ++d)
            acc2 = fmaf(hrow[d], wcb[(size_t)d * NH], acc2);
        acc2 += __shfl_xor(acc2, 1, 64);
        acc2 += __shfl_xor(acc2, 2, 64);
        acc2 += __shfl_xor(acc2, 4, 64);
        if (q == 0) {
            const float x = acc2 + bb[hh];
            // stable softplus: max(x,0) + log1p(exp(-|x|))
            bts[ii][hh] = fmaxf(x, 0.f) + log1pf(expf(-fabsf(x)));
        }
    }
    __syncthreads();

    // ---- Phase C: attention, one wave per batch, no barriers --------------
    const int lane = t & 63;
    const int wid  = t >> 6;          // 0..7

#pragma unroll
    for (int p = 0; p < 2; ++p) {
        const int bl = p * 8 + wid;   // local batch 0..15
        const int b  = i0 + bl;

        const float4* row0 = (const float4*)(mem + (size_t)b * (M * W) + (size_t)lane * W);
        const float4* row1 = row0 + (64 * W / 4);   // row lane+64

        float v2a = 0.f, v2b = 0.f;
        float na[NH] = {0.f, 0.f, 0.f, 0.f};
        float nb[NH] = {0.f, 0.f, 0.f, 0.f};
#pragma unroll
        for (int c = 0; c < 16; ++c) {
            const float4 x0 = row0[c];
            const float4 x1 = row1[c];
            v2a = fmaf(x0.x, x0.x, fmaf(x0.y, x0.y, fmaf(x0.z, x0.z, fmaf(x0.w, x0.w, v2a))));
            v2b = fmaf(x1.x, x1.x, fmaf(x1.y, x1.y, fmaf(x1.z, x1.z, fmaf(x1.w, x1.w, v2b))));
#pragma unroll
            for (int h = 0; h < NH; ++h) {
                const float4 kk = *(const float4*)&kl[bl][h * W + c * 4];
                na[h] = fmaf(x0.x, kk.x, fmaf(x0.y, kk.y, fmaf(x0.z, kk.z, fmaf(x0.w, kk.w, na[h]))));
                nb[h] = fmaf(x1.x, kk.x, fmaf(x1.y, kk.y, fmaf(x1.z, kk.z, fmaf(x1.w, kk.w, nb[h]))));
            }
        }
        v2a += EPS;
        v2b += EPS;

        float la[NH], lb[NH];
#pragma unroll
        for (int h = 0; h < NH; ++h) {
            const float u2 = u2s[bl][h];
            const float bt = bts[bl][h];
            la[h] = (na[h] / (sqrtf(u2 * v2a) + EPS)) * bt;
            lb[h] = (nb[h] / (sqrtf(u2 * v2b) + EPS)) * bt;
        }

        // in-wave softmax over the 128 rows (2 per lane), per head
#pragma unroll
        for (int h = 0; h < NH; ++h) {
            float m_ = fmaxf(la[h], lb[h]);
#pragma unroll
            for (int off = 1; off < 64; off <<= 1)
                m_ = fmaxf(m_, __shfl_xor(m_, off, 64));
            const float ea = expf(la[h] - m_);
            const float eb = expf(lb[h] - m_);
            float s_ = ea + eb;
#pragma unroll
            for (int off = 1; off < 64; off <<= 1)
                s_ += __shfl_xor(s_, off, 64);
            out[(size_t)b * (NH * M) + (size_t)h * M + lane]      = ea / s_;
            out[(size_t)b * (NH * M) + (size_t)h * M + lane + 64] = eb / s_;
        }
    }
}

// ---------------------------------------------------------------------------
extern "C" void kernel_launch(void* const* d_in, const int* in_sizes, int n_in,
                              void* d_out, int out_size, void* d_ws, size_t ws_size,
                              hipStream_t stream) {
    const float* hid = (const float*)d_in[0];  // [B, D]
    const float* mem = (const float*)d_in[1];  // [B, M, W]
    const float* Wk  = (const float*)d_in[2];  // [D, HW]
    const float* bk  = (const float*)d_in[3];  // [HW]
    const float* Wb  = (const float*)d_in[4];  // [D, NH]
    const float* bb  = (const float*)d_in[5];  // [NH]
    float* out = (float*)d_out;                // [B, NH, M]

    (void)d_ws; (void)ws_size;  // fully fused: no workspace needed

    fused_dynhead<<<B / TILE, 512, 0, stream>>>(hid, mem, Wk, bk, Wb, bb, out);
}